// Round 7
// baseline (557.360 us; speedup 1.0000x reference)
//
#include <hip/hip_runtime.h>
#include <hip/hip_bf16.h>

// Problem constants
#define BS_   32
#define LQ_   300
#define LV_   13294
#define EMBED_ 256
#define HEADS_ 8
#define HEAD_DIM_ 32
#define NCHUNK_ 13294   /* 425408 / 32 */
#define NSTREAM_ 1536   /* 256 blocks * 6 pairs */

typedef __attribute__((ext_vector_type(8))) short bf16x8;
typedef __attribute__((ext_vector_type(4))) float f32x4;

__device__ inline short f2bf(float f) {   // RNE fp32->bf16 (bit trick)
  union { float f; unsigned u; } x; x.f = f;
  return (short)((x.u + 0x7FFF + ((x.u >> 16) & 1)) >> 16);
}
__device__ inline short f2bf_i(float f) { // via HW cvt
  union { __hip_bfloat16 h; short s; } u;
  u.h = __float2bfloat16(f);
  return u.s;
}
__device__ inline float bf2f(short s) {
  union { unsigned u; float f; } x; x.u = ((unsigned)(unsigned short)s) << 16;
  return x.f;
}

// async global->LDS, 16B per lane (used by the small query-side GEMM only)
__device__ __forceinline__ void gld_lds16(const void* g, void* l) {
  __builtin_amdgcn_global_load_lds(
      (const __attribute__((address_space(1))) unsigned int*)g,
      (__attribute__((address_space(3))) unsigned int*)l, 16, 0, 0);
}

// ---------------------------------------------------------------------------
// W [256 k][Nsrc n] fp32 -> Wt [256 n][256 k] bf16, zero-padded cols >= Nsrc.
// ---------------------------------------------------------------------------
__global__ void convert_wt(const float* __restrict__ W, short* __restrict__ Wt,
                           int Nsrc) {
  const int n = blockIdx.x;   // 0..255
  const int k = threadIdx.x;  // 0..255
  Wt[n * 256 + k] = (n < Nsrc) ? f2bf(W[k * Nsrc + n]) : (short)0;
}

// ---------------------------------------------------------------------------
// TLP-stream value GEMM: Vp = bf16(value @ W_val + b_val), [b][h][pos][32].
// Grid = 256 blocks x 768 thr (12 waves). B (256x256 bf16 = 128 KB) staged
// once into LDS (XOR-swizzled granules, both sides) -> ONE barrier total.
// Then waves stream independently, no sync: wave-pair (2i, 2i+1) processes
// 32-row chunks c = bid*6 + i (+1536 stride); wave j of pair owns cols
// j*128..+127. A: global->reg fp32, named 2-deep pipeline, cvt->bf16.
// acc[2 mf][8 nf] f32x4 = 64 VGPR. Epilogue: direct scalar bf16 stores
// (no write amplification per R4/R5 WRITE_SIZE; issue cost negligible).
// Latency model: 12 indep waves x 2KB/kt covers the 24.6 GB/s per-CU HBM
// share 2.7x over even with zero ILP; LDS b128 demand ~49% of per-CU peak.
// ---------------------------------------------------------------------------
__global__ __launch_bounds__(768, 3) void gemm_value_stream(
    const float* __restrict__ A, const short* __restrict__ Wt,
    const float* __restrict__ bias, short* __restrict__ Vp) {
  __shared__ short Bl[65536];   // 128 KB: [n][32 granules of 8 shorts], swizzled

  const int tid = threadIdx.x;
  const int lane = tid & 63;
  const int w = tid >> 6;        // 0..11
  const int pair = w >> 1;       // 0..5
  const int j = w & 1;           // column half
  const int lr = lane & 15;
  const int lkq = lane >> 4;     // k-quarter

  // ---- stage B global->reg->swizzled ds_write (once per block) ----
  // granule g of row n lands at LDS granule (g ^ (n&7)) within row n.
  for (int g = tid; g < 8192; g += 768) {
    const int n = g >> 5;
    const int gk = g & 31;
    const bf16x8 v = *(const bf16x8*)(Wt + n * 256 + gk * 8);
    *(bf16x8*)(Bl + n * 256 + ((gk ^ (n & 7)) * 8)) = v;
  }

  float bv[8];
#pragma unroll
  for (int nf = 0; nf < 8; ++nf) bv[nf] = bias[j * 128 + nf * 16 + lr];

  __syncthreads();   // the only block-wide barrier

  const int ssw = lr & 7;                  // read-side XOR (n&7 == lr&7 here)
  const int base2 = (j * 128 + lr) * 256;  // short-offset of row n(nf=0)

#define COMPUTE(kt, ra0, rb0, ra1, rb1)                                        \
  do {                                                                         \
    bf16x8 af0, af1;                                                           \
    _Pragma("unroll") for (int i = 0; i < 4; ++i) {                            \
      af0[i] = f2bf_i(ra0[i]); af0[i + 4] = f2bf_i(rb0[i]);                    \
      af1[i] = f2bf_i(ra1[i]); af1[i + 4] = f2bf_i(rb1[i]);                    \
    }                                                                          \
    const short* bp_ = Bl + base2 + ((((kt) * 4 + lkq) ^ ssw) * 8);            \
    _Pragma("unroll") for (int nf = 0; nf < 8; ++nf) {                         \
      const bf16x8 bf = *(const bf16x8*)(bp_ + nf * 4096);                     \
      acc[0][nf] = __builtin_amdgcn_mfma_f32_16x16x32_bf16(af0, bf, acc[0][nf], 0, 0, 0); \
      acc[1][nf] = __builtin_amdgcn_mfma_f32_16x16x32_bf16(af1, bf, acc[1][nf], 0, 0, 0); \
    }                                                                          \
  } while (0)

  for (int c = blockIdx.x * 6 + pair; c < NCHUNK_; c += NSTREAM_) {
    const float* a0p = A + (size_t)(c * 32 + lr) * 256 + lkq * 8;
    const float* a1p = a0p + 16 * 256;

    f32x4 acc[2][8];
#pragma unroll
    for (int i = 0; i < 2; ++i)
#pragma unroll
      for (int nf = 0; nf < 8; ++nf) acc[i][nf] = (f32x4){0.f, 0.f, 0.f, 0.f};

    // named 2-deep A pipeline (rule #20: no runtime-indexed reg arrays)
    f32x4 x0a = *(const f32x4*)(a0p),     x0b = *(const f32x4*)(a0p + 4);
    f32x4 x1a = *(const f32x4*)(a1p),     x1b = *(const f32x4*)(a1p + 4);
    f32x4 y0a, y0b, y1a, y1b;
#pragma unroll
    for (int k2 = 0; k2 < 4; ++k2) {
      const int ko1 = (2 * k2 + 1) * 32;
      y0a = *(const f32x4*)(a0p + ko1); y0b = *(const f32x4*)(a0p + ko1 + 4);
      y1a = *(const f32x4*)(a1p + ko1); y1b = *(const f32x4*)(a1p + ko1 + 4);
      COMPUTE(2 * k2, x0a, x0b, x1a, x1b);
      if (k2 < 3) {
        const int ko2 = (2 * k2 + 2) * 32;
        x0a = *(const f32x4*)(a0p + ko2); x0b = *(const f32x4*)(a0p + ko2 + 4);
        x1a = *(const f32x4*)(a1p + ko2); x1b = *(const f32x4*)(a1p + ko2 + 4);
      }
      COMPUTE(2 * k2 + 1, y0a, y0b, y1a, y1b);
    }

    // direct scalar bf16 stores (D map: col=lane&15, row=lkq*4+rr)
#pragma unroll
    for (int mf = 0; mf < 2; ++mf)
#pragma unroll
      for (int rr = 0; rr < 4; ++rr) {
        const unsigned m = (unsigned)c * 32 + mf * 16 + lkq * 4 + rr;
        const unsigned b_ = m / LV_;
        const unsigned pos = m - b_ * LV_;
#pragma unroll
        for (int nf = 0; nf < 8; ++nf) {
          const int n = j * 128 + nf * 16 + lr;
          Vp[((size_t)(b_ * HEADS_ + (n >> 5)) * LV_ + pos) * HEAD_DIM_ + (n & 31)] =
              f2bf(acc[mf][nf][rr] + bv[nf]);
        }
      }
  }
#undef COMPUTE
}

// ---------------------------------------------------------------------------
// Query-side GEMM (small M): C[M,256] = A[M,256] @ Wt^T + bias, f32 out.
// bigA structure from R6 (B slice in regs, A staged once, one barrier).
// ---------------------------------------------------------------------------
__global__ __launch_bounds__(256, 2) void gemm_qproj(
    const float* __restrict__ A, const short* __restrict__ Wt,
    const float* __restrict__ bias, float* __restrict__ C,
    int ldc, int Nbias) {
  __shared__ float As[64 * 256];

  const int tid = threadIdx.x;
  const int lane = tid & 63;
  const int w = tid >> 6;
  const int n0 = w * 64;
  const size_t m0 = (size_t)blockIdx.x * 64;
  const int lr = lane & 15;
  const int lkq = lane >> 4;

#pragma unroll
  for (int i = 0; i < 16; ++i) {
    const int row = w * 16 + i;
    gld_lds16(A + (m0 + row) * 256 + ((lane ^ (row & 7)) * 4), As + row * 256);
  }

  bf16x8 bfr[4][8];
#pragma unroll
  for (int nf = 0; nf < 4; ++nf) {
    const size_t bbase = (size_t)(n0 + nf * 16 + lr) * 256 + lkq * 8;
#pragma unroll
    for (int kt = 0; kt < 8; ++kt)
      bfr[nf][kt] = *(const bf16x8*)(Wt + bbase + kt * 32);
  }

  f32x4 acc[4][4];
#pragma unroll
  for (int i = 0; i < 4; ++i)
#pragma unroll
    for (int jj = 0; jj < 4; ++jj) acc[i][jj] = (f32x4){0.f, 0.f, 0.f, 0.f};

  __syncthreads();

#pragma unroll
  for (int kt = 0; kt < 8; ++kt) {
#pragma unroll
    for (int mf = 0; mf < 4; ++mf) {
      const int row = mf * 16 + lr;
      const int gbase = kt * 8 + lkq * 2;
      const f32x4 a0 = *(const f32x4*)(As + row * 256 + ((gbase) ^ (row & 7)) * 4);
      const f32x4 a1 = *(const f32x4*)(As + row * 256 + ((gbase + 1) ^ (row & 7)) * 4);
      bf16x8 af;
#pragma unroll
      for (int i = 0; i < 4; ++i) {
        af[i]     = f2bf_i(a0[i]);
        af[i + 4] = f2bf_i(a1[i]);
      }
#pragma unroll
      for (int nf = 0; nf < 4; ++nf)
        acc[mf][nf] = __builtin_amdgcn_mfma_f32_16x16x32_bf16(af, bfr[nf][kt], acc[mf][nf], 0, 0, 0);
    }
  }

  float bv[4];
#pragma unroll
  for (int nf = 0; nf < 4; ++nf) {
    const int n = n0 + nf * 16 + lr;
    bv[nf] = (n < Nbias) ? bias[n] : 0.f;
  }
  const int lq4 = lkq * 4;
#pragma unroll
  for (int mf = 0; mf < 4; ++mf)
#pragma unroll
    for (int r = 0; r < 4; ++r) {
      const size_t m = m0 + mf * 16 + lq4 + r;
#pragma unroll
      for (int nf = 0; nf < 4; ++nf) {
        const int n = n0 + nf * 16 + lr;
        C[m * ldc + n] = acc[mf][nf][r] + bv[nf];
      }
    }
}

// ---------------------------------------------------------------------------
// Softmax over 16 per (row, head); logits row-stride 256 (cols 128+ unused).
// ---------------------------------------------------------------------------
__global__ void softmax16(const float* __restrict__ logits,
                          float* __restrict__ attn, int ngroups) {
  const int g = blockIdx.x * blockDim.x + threadIdx.x;
  if (g >= ngroups) return;
  const int row = g >> 3, h = g & 7;
  const float* in = logits + (size_t)row * 256 + h * 16;
  float v[16];
  float m = -1e30f;
#pragma unroll
  for (int i = 0; i < 16; ++i) { v[i] = in[i]; m = fmaxf(m, v[i]); }
  float s = 0.f;
#pragma unroll
  for (int i = 0; i < 16; ++i) { v[i] = __expf(v[i] - m); s += v[i]; }
  const float inv = 1.0f / s;
  float* out = attn + (size_t)g * 16;
#pragma unroll
  for (int i = 0; i < 16; ++i) out[i] = v[i] * inv;
}

// ---------------------------------------------------------------------------
// Deformable sampling: one thread per (b, q, head, 8-channel group).
// ---------------------------------------------------------------------------
__global__ __launch_bounds__(256) void msda_sample(
    const float* __restrict__ ref_pts,   // [BS*LQ, 4, 2]
    const float* __restrict__ offsets,   // [BS*LQ, 256]  (h,l,p,2)
    const float* __restrict__ attn,      // [BS*LQ, 128]  (h,l,p)
    const short* __restrict__ value_p,   // [b,h,pos,32] bf16
    float* __restrict__ tmp)             // [BS*LQ, 256]
{
  const int t = blockIdx.x * 256 + threadIdx.x;
  const int c8 = t & 3;
  const int h = (t >> 2) & 7;
  const int row = t >> 5;
  const int b = row / LQ_;

  const int HS[4] = {100, 50, 25, 13};
  const int START[4] = {0, 10000, 12500, 13125};

  const float* offr = offsets + (size_t)row * 256 + h * 32;
  const float* attr = attn + (size_t)row * 128 + h * 16;
  const float* refr = ref_pts + (size_t)row * 8;

  float acc[8];
#pragma unroll
  for (int jj = 0; jj < 8; ++jj) acc[jj] = 0.f;

#pragma unroll
  for (int l = 0; l < 4; ++l) {
    const int HH = HS[l];
    const int WW = HS[l];
    const float fH = (float)HH, fW = (float)WW;
    const float rx = refr[l * 2 + 0];
    const float ry = refr[l * 2 + 1];
    const short* vbase =
        value_p + ((size_t)(b * HEADS_ + h) * LV_ + START[l]) * HEAD_DIM_ + c8 * 8;
#pragma unroll
    for (int p = 0; p < 4; ++p) {
      const float ox = offr[(l * 4 + p) * 2 + 0];
      const float oy = offr[(l * 4 + p) * 2 + 1];
      const float x = (rx + ox / fW) * fW - 0.5f;
      const float y = (ry + oy / fH) * fH - 0.5f;
      const float x0f = floorf(x), y0f = floorf(y);
      const float fx = x - x0f, fy = y - y0f;
      const int x0 = (int)x0f, y0 = (int)y0f;
      const float wgt = attr[l * 4 + p];
      const float iy0 = (y0 >= 0 && y0 < HH) ? 1.f : 0.f;
      const float iy1 = (y0 + 1 >= 0 && y0 + 1 < HH) ? 1.f : 0.f;
      const float ix0 = (x0 >= 0 && x0 < WW) ? 1.f : 0.f;
      const float ix1 = (x0 + 1 >= 0 && x0 + 1 < WW) ? 1.f : 0.f;
      const float w00 = (1.f - fy) * (1.f - fx) * wgt * iy0 * ix0;
      const float w01 = (1.f - fy) * fx * wgt * iy0 * ix1;
      const float w10 = fy * (1.f - fx) * wgt * iy1 * ix0;
      const float w11 = fy * fx * wgt * iy1 * ix1;
      const int xc0 = min(max(x0, 0), WW - 1);
      const int xc1 = min(max(x0 + 1, 0), WW - 1);
      const int yc0 = min(max(y0, 0), HH - 1);
      const int yc1 = min(max(y0 + 1, 0), HH - 1);
      const bf16x8 q00 = *(const bf16x8*)(vbase + (size_t)(yc0 * WW + xc0) * HEAD_DIM_);
      const bf16x8 q01 = *(const bf16x8*)(vbase + (size_t)(yc0 * WW + xc1) * HEAD_DIM_);
      const bf16x8 q10 = *(const bf16x8*)(vbase + (size_t)(yc1 * WW + xc0) * HEAD_DIM_);
      const bf16x8 q11 = *(const bf16x8*)(vbase + (size_t)(yc1 * WW + xc1) * HEAD_DIM_);
#pragma unroll
      for (int jj = 0; jj < 8; ++jj) {
        acc[jj] += w00 * bf2f(q00[jj]) + w01 * bf2f(q01[jj]) +
                   w10 * bf2f(q10[jj]) + w11 * bf2f(q11[jj]);
      }
    }
  }
  float* o = tmp + (size_t)row * 256 + h * 32 + c8 * 8;
  f32x4 o0 = {acc[0], acc[1], acc[2], acc[3]};
  f32x4 o1 = {acc[4], acc[5], acc[6], acc[7]};
  *(f32x4*)(o) = o0;
  *(f32x4*)(o + 4) = o1;
}

// ---------------------------------------------------------------------------
extern "C" void kernel_launch(void* const* d_in, const int* in_sizes, int n_in,
                              void* d_out, int out_size, void* d_ws, size_t ws_size,
                              hipStream_t stream) {
  const float* query  = (const float*)d_in[0];
  const float* refpts = (const float*)d_in[1];
  const float* value  = (const float*)d_in[2];
  const float* W_off  = (const float*)d_in[4];
  const float* b_off  = (const float*)d_in[5];
  const float* W_attn = (const float*)d_in[6];
  const float* b_attn = (const float*)d_in[7];
  const float* W_val  = (const float*)d_in[8];
  const float* b_val  = (const float*)d_in[9];
  const float* W_out  = (const float*)d_in[10];
  const float* b_out  = (const float*)d_in[11];
  float* out = (float*)d_out;

  char* ws = (char*)d_ws;
  short* value_p = (short*)ws;                                 // 217,710,592 B
  size_t off = (size_t)BS_ * HEADS_ * LV_ * HEAD_DIM_ * 2;
  float* offsets = (float*)(ws + off); off += (size_t)BS_ * LQ_ * 256 * 4;
  float* attn    = (float*)(ws + off); off += (size_t)BS_ * LQ_ * 128 * 4;
  float* tmp     = (float*)(ws + off); off += (size_t)BS_ * LQ_ * 256 * 4;

  // Aliasing plan (stream-sequential ordering makes each safe):
  //  WtA/WtB in value_p[0:256KB): consumed by query GEMMs BEFORE the
  //    value GEMM overwrites value_p.
  //  logits = tmp: written by attn GEMM, consumed by softmax.
  //  WtV = tmp[0:128KB): written after logits dead; read only during
  //    gemm_value_stream's B-staging; overwritten by sampler output later.
  //  WtO = value_p[0:128KB): written AFTER sampler has read value_p.
  short* WtA = (short*)value_p;
  short* WtB = (short*)value_p + 256 * 256;
  float* logits = tmp;
  short* WtV = (short*)tmp;
  short* WtO = (short*)value_p;

  const int MQ = BS_ * LQ_;   // 9600 = 64*150

  convert_wt<<<256, 256, 0, stream>>>(W_off, WtA, 256);
  convert_wt<<<256, 256, 0, stream>>>(W_attn, WtB, 128);
  gemm_qproj<<<MQ / 64, 256, 0, stream>>>(query, WtA, b_off, offsets, 256, 256);
  gemm_qproj<<<MQ / 64, 256, 0, stream>>>(query, WtB, b_attn, logits, 256, 128);
  softmax16<<<(MQ * HEADS_ + 255) / 256, 256, 0, stream>>>(logits, attn, MQ * HEADS_);
  convert_wt<<<256, 256, 0, stream>>>(W_val, WtV, 256);
  gemm_value_stream<<<256, 768, 0, stream>>>(value, WtV, b_val, value_p);
  msda_sample<<<(MQ * 32) / 256, 256, 0, stream>>>(refpts, offsets, attn, value_p, tmp);
  convert_wt<<<256, 256, 0, stream>>>(W_out, WtO, 256);
  gemm_qproj<<<MQ / 64, 256, 0, stream>>>(tmp, WtO, b_out, out, 256, 256);
}

// Round 8
// 228.122 us; speedup vs baseline: 2.4433x; 2.4433x over previous
//
#include <hip/hip_runtime.h>
#include <hip/hip_bf16.h>

// Problem constants
#define BS_   32
#define LQ_   300
#define LV_   13294
#define EMBED_ 256
#define HEADS_ 8
#define HEAD_DIM_ 32
#define NCHUNK_ 13294   /* 425408 rows / 32 rows per chunk */
#define PSTRIDE_ 512    /* persistent grid size */

typedef __attribute__((ext_vector_type(8))) short bf16x8;
typedef __attribute__((ext_vector_type(4))) float f32x4;

__device__ inline short f2bf(float f) {   // RNE fp32->bf16 (bit trick)
  union { float f; unsigned u; } x; x.f = f;
  return (short)((x.u + 0x7FFF + ((x.u >> 16) & 1)) >> 16);
}
__device__ inline short f2bf_i(float f) { // via HW cvt
  union { __hip_bfloat16 h; short s; } u;
  u.h = __float2bfloat16(f);
  return u.s;
}
__device__ inline float bf2f(short s) {
  union { unsigned u; float f; } x; x.u = ((unsigned)(unsigned short)s) << 16;
  return x.f;
}

// async global->LDS, 16B per lane. LDS dest = wave-uniform base + lane*16.
__device__ __forceinline__ void gld_lds16(const void* g, void* l) {
  __builtin_amdgcn_global_load_lds(
      (const __attribute__((address_space(1))) unsigned int*)g,
      (__attribute__((address_space(3))) unsigned int*)l, 16, 0, 0);
}

// ---------------------------------------------------------------------------
// W [256 k][Nsrc n] fp32 -> Wt [256 n][256 k] bf16, zero-padded cols >= Nsrc.
// ---------------------------------------------------------------------------
__global__ void convert_wt(const float* __restrict__ W, short* __restrict__ Wt,
                           int Nsrc) {
  const int n = blockIdx.x;   // 0..255
  const int k = threadIdx.x;  // 0..255
  Wt[n * 256 + k] = (n < Nsrc) ? f2bf(W[k * Nsrc + n]) : (short)0;
}

// ---------------------------------------------------------------------------
// Persistent chunk-pipelined value GEMM: Vp = bf16(value @ W_val + b_val),
// layout [b][h][pos][32]. Grid 512 x 512 thr (8 waves). Wave w owns cols
// w*32..+31 (== head h=w); B slice bfr[2 nf][8 kt] = 64 VGPR, loaded once
// from L2-resident Wt. A: 32-row x 256-col fp32 chunk (32 KB) staged via
// global_load_lds into 2-deep LDS ring (64 KB total). Per chunk:
//   stage(next)  [4 gld_lds/wave, issued right after the barrier]
//   compute(cur) [32 ds_read_b128 + 32 cvt_pk-ish + 32 MFMA /wave]
//   store(cur)   [16 scalar bf16 stores/wave; fire-and-forget]
//   s_waitcnt vmcnt(16)  <- retires ONLY the 4 oldest (the stage); the 16
//                           stores stay in flight. Never vmcnt(0) in loop.
//   s_barrier
// WAR: stage(next) writes buf^1, whose readers all passed the prior barrier.
// RAW: own-wave vmcnt + barrier => whole chunk resident before any read.
// Swizzle (both-sides, rule #21): A granule g of row r lands at LDS granule
// g^(r&7); frag reads XOR the same -> ~2-way bank aliasing (free).
// ---------------------------------------------------------------------------
__global__ __launch_bounds__(512, 2) void gemm_value_persist(
    const float* __restrict__ A, const short* __restrict__ Wt,
    const float* __restrict__ bias, short* __restrict__ Vp) {
  __shared__ float As[2][32 * 256];   // 2 x 32 KB

  const int tid = threadIdx.x;
  const int lane = tid & 63;
  const int w = tid >> 6;        // wave 0..7; also the head this wave owns
  const int lr = lane & 15;
  const int lkq = lane >> 4;     // k-quarter

  // ---- B slice -> registers (16 x 16B loads, L2-resident) ----
  bf16x8 bfr[2][8];
#pragma unroll
  for (int nf = 0; nf < 2; ++nf) {
    const size_t bbase = (size_t)(w * 32 + nf * 16 + lr) * 256 + lkq * 8;
#pragma unroll
    for (int kt = 0; kt < 8; ++kt)
      bfr[nf][kt] = *(const bf16x8*)(Wt + bbase + kt * 32);
  }
  float bv[2];
#pragma unroll
  for (int nf = 0; nf < 2; ++nf) bv[nf] = bias[w * 32 + nf * 16 + lr];

  // stage: wave w stages rows w*4 .. w*4+3 of the chunk (1 row = 1 KB/instr)
  auto stage = [&](int buf, int c) {
    const float* src = A + (size_t)c * (32 * 256);
#pragma unroll
    for (int i = 0; i < 4; ++i) {
      const int r = w * 4 + i;
      gld_lds16(src + r * 256 + ((lane ^ (r & 7)) * 4), &As[buf][r * 256]);
    }
  };

  const int c0 = blockIdx.x;
  stage(0, c0);
  asm volatile("s_waitcnt vmcnt(0)" ::: "memory");
  __syncthreads();

  int cb = 0;
  for (int c = c0; c < NCHUNK_; c += PSTRIDE_) {
    const int nxt = c + PSTRIDE_;
    if (nxt < NCHUNK_) stage(cb ^ 1, nxt);

    // ---- compute chunk c from As[cb] ----
    f32x4 acc[2][2];
#pragma unroll
    for (int i = 0; i < 2; ++i)
#pragma unroll
      for (int jj = 0; jj < 2; ++jj) acc[i][jj] = (f32x4){0.f, 0.f, 0.f, 0.f};

    const float* as = &As[cb][0];
#pragma unroll
    for (int kt = 0; kt < 8; ++kt) {
      const int r0 = lr;          // mf=0 row
      const int r1 = 16 + lr;     // mf=1 row
      const int g = kt * 8 + lkq * 2;
      const f32x4 a00 = *(const f32x4*)(as + r0 * 256 + (((g    ) ^ (r0 & 7)) * 4));
      const f32x4 a01 = *(const f32x4*)(as + r0 * 256 + (((g + 1) ^ (r0 & 7)) * 4));
      const f32x4 a10 = *(const f32x4*)(as + r1 * 256 + (((g    ) ^ (r1 & 7)) * 4));
      const f32x4 a11 = *(const f32x4*)(as + r1 * 256 + (((g + 1) ^ (r1 & 7)) * 4));
      bf16x8 af0, af1;
#pragma unroll
      for (int i = 0; i < 4; ++i) {
        af0[i]     = f2bf_i(a00[i]);
        af0[i + 4] = f2bf_i(a01[i]);
        af1[i]     = f2bf_i(a10[i]);
        af1[i + 4] = f2bf_i(a11[i]);
      }
      acc[0][0] = __builtin_amdgcn_mfma_f32_16x16x32_bf16(af0, bfr[0][kt], acc[0][0], 0, 0, 0);
      acc[0][1] = __builtin_amdgcn_mfma_f32_16x16x32_bf16(af0, bfr[1][kt], acc[0][1], 0, 0, 0);
      acc[1][0] = __builtin_amdgcn_mfma_f32_16x16x32_bf16(af1, bfr[0][kt], acc[1][0], 0, 0, 0);
      acc[1][1] = __builtin_amdgcn_mfma_f32_16x16x32_bf16(af1, bfr[1][kt], acc[1][1], 0, 0, 0);
    }

    // ---- store chunk c (16 scalar bf16 stores; D map col=lr, row=lkq*4+rr) ----
#pragma unroll
    for (int mf = 0; mf < 2; ++mf)
#pragma unroll
      for (int rr = 0; rr < 4; ++rr) {
        const unsigned m = (unsigned)c * 32 + mf * 16 + lkq * 4 + rr;
        const unsigned b_ = m / LV_;
        const unsigned pos = m - b_ * LV_;
        const size_t rowbase = ((size_t)(b_ * HEADS_ + w) * LV_ + pos) * HEAD_DIM_;
#pragma unroll
        for (int nf = 0; nf < 2; ++nf)
          Vp[rowbase + nf * 16 + lr] = f2bf(acc[mf][nf][rr] + bv[nf]);
      }

    if (nxt < NCHUNK_) {
      asm volatile("s_waitcnt vmcnt(16)" ::: "memory");  // stage landed; stores in flight
      asm volatile("s_barrier" ::: "memory");
    }
    cb ^= 1;
  }
}

// ---------------------------------------------------------------------------
// Query-side GEMM (small M): C[M,256] = A[M,256] @ Wt^T + bias, f32 out.
// R6 bigA structure (B slice in regs, A staged once, one barrier).
// ---------------------------------------------------------------------------
__global__ __launch_bounds__(256, 2) void gemm_qproj(
    const float* __restrict__ A, const short* __restrict__ Wt,
    const float* __restrict__ bias, float* __restrict__ C,
    int ldc, int Nbias) {
  __shared__ float As[64 * 256];

  const int tid = threadIdx.x;
  const int lane = tid & 63;
  const int w = tid >> 6;
  const int n0 = w * 64;
  const size_t m0 = (size_t)blockIdx.x * 64;
  const int lr = lane & 15;
  const int lkq = lane >> 4;

#pragma unroll
  for (int i = 0; i < 16; ++i) {
    const int row = w * 16 + i;
    gld_lds16(A + (m0 + row) * 256 + ((lane ^ (row & 7)) * 4), As + row * 256);
  }

  bf16x8 bfr[4][8];
#pragma unroll
  for (int nf = 0; nf < 4; ++nf) {
    const size_t bbase = (size_t)(n0 + nf * 16 + lr) * 256 + lkq * 8;
#pragma unroll
    for (int kt = 0; kt < 8; ++kt)
      bfr[nf][kt] = *(const bf16x8*)(Wt + bbase + kt * 32);
  }

  f32x4 acc[4][4];
#pragma unroll
  for (int i = 0; i < 4; ++i)
#pragma unroll
    for (int jj = 0; jj < 4; ++jj) acc[i][jj] = (f32x4){0.f, 0.f, 0.f, 0.f};

  __syncthreads();

#pragma unroll
  for (int kt = 0; kt < 8; ++kt) {
#pragma unroll
    for (int mf = 0; mf < 4; ++mf) {
      const int row = mf * 16 + lr;
      const int gbase = kt * 8 + lkq * 2;
      const f32x4 a0 = *(const f32x4*)(As + row * 256 + ((gbase) ^ (row & 7)) * 4);
      const f32x4 a1 = *(const f32x4*)(As + row * 256 + ((gbase + 1) ^ (row & 7)) * 4);
      bf16x8 af;
#pragma unroll
      for (int i = 0; i < 4; ++i) {
        af[i]     = f2bf_i(a0[i]);
        af[i + 4] = f2bf_i(a1[i]);
      }
#pragma unroll
      for (int nf = 0; nf < 4; ++nf)
        acc[mf][nf] = __builtin_amdgcn_mfma_f32_16x16x32_bf16(af, bfr[nf][kt], acc[mf][nf], 0, 0, 0);
    }
  }

  float bv[4];
#pragma unroll
  for (int nf = 0; nf < 4; ++nf) {
    const int n = n0 + nf * 16 + lr;
    bv[nf] = (n < Nbias) ? bias[n] : 0.f;
  }
  const int lq4 = lkq * 4;
#pragma unroll
  for (int mf = 0; mf < 4; ++mf)
#pragma unroll
    for (int r = 0; r < 4; ++r) {
      const size_t m = m0 + mf * 16 + lq4 + r;
#pragma unroll
      for (int nf = 0; nf < 4; ++nf) {
        const int n = n0 + nf * 16 + lr;
        C[m * ldc + n] = acc[mf][nf][r] + bv[nf];
      }
    }
}

// ---------------------------------------------------------------------------
// Softmax over 16 per (row, head); logits row-stride 256 (cols 128+ unused).
// ---------------------------------------------------------------------------
__global__ void softmax16(const float* __restrict__ logits,
                          float* __restrict__ attn, int ngroups) {
  const int g = blockIdx.x * blockDim.x + threadIdx.x;
  if (g >= ngroups) return;
  const int row = g >> 3, h = g & 7;
  const float* in = logits + (size_t)row * 256 + h * 16;
  float v[16];
  float m = -1e30f;
#pragma unroll
  for (int i = 0; i < 16; ++i) { v[i] = in[i]; m = fmaxf(m, v[i]); }
  float s = 0.f;
#pragma unroll
  for (int i = 0; i < 16; ++i) { v[i] = __expf(v[i] - m); s += v[i]; }
  const float inv = 1.0f / s;
  float* out = attn + (size_t)g * 16;
#pragma unroll
  for (int i = 0; i < 16; ++i) out[i] = v[i] * inv;
}

// ---------------------------------------------------------------------------
// Deformable sampling: one thread per (b, q, head, 8-channel group).
// ---------------------------------------------------------------------------
__global__ __launch_bounds__(256) void msda_sample(
    const float* __restrict__ ref_pts,   // [BS*LQ, 4, 2]
    const float* __restrict__ offsets,   // [BS*LQ, 256]  (h,l,p,2)
    const float* __restrict__ attn,      // [BS*LQ, 128]  (h,l,p)
    const short* __restrict__ value_p,   // [b,h,pos,32] bf16
    float* __restrict__ tmp)             // [BS*LQ, 256]
{
  const int t = blockIdx.x * 256 + threadIdx.x;
  const int c8 = t & 3;
  const int h = (t >> 2) & 7;
  const int row = t >> 5;
  const int b = row / LQ_;

  const int HS[4] = {100, 50, 25, 13};
  const int START[4] = {0, 10000, 12500, 13125};

  const float* offr = offsets + (size_t)row * 256 + h * 32;
  const float* attr = attn + (size_t)row * 128 + h * 16;
  const float* refr = ref_pts + (size_t)row * 8;

  float acc[8];
#pragma unroll
  for (int jj = 0; jj < 8; ++jj) acc[jj] = 0.f;

#pragma unroll
  for (int l = 0; l < 4; ++l) {
    const int HH = HS[l];
    const int WW = HS[l];
    const float fH = (float)HH, fW = (float)WW;
    const float rx = refr[l * 2 + 0];
    const float ry = refr[l * 2 + 1];
    const short* vbase =
        value_p + ((size_t)(b * HEADS_ + h) * LV_ + START[l]) * HEAD_DIM_ + c8 * 8;
#pragma unroll
    for (int p = 0; p < 4; ++p) {
      const float ox = offr[(l * 4 + p) * 2 + 0];
      const float oy = offr[(l * 4 + p) * 2 + 1];
      const float x = (rx + ox / fW) * fW - 0.5f;
      const float y = (ry + oy / fH) * fH - 0.5f;
      const float x0f = floorf(x), y0f = floorf(y);
      const float fx = x - x0f, fy = y - y0f;
      const int x0 = (int)x0f, y0 = (int)y0f;
      const float wgt = attr[l * 4 + p];
      const float iy0 = (y0 >= 0 && y0 < HH) ? 1.f : 0.f;
      const float iy1 = (y0 + 1 >= 0 && y0 + 1 < HH) ? 1.f : 0.f;
      const float ix0 = (x0 >= 0 && x0 < WW) ? 1.f : 0.f;
      const float ix1 = (x0 + 1 >= 0 && x0 + 1 < WW) ? 1.f : 0.f;
      const float w00 = (1.f - fy) * (1.f - fx) * wgt * iy0 * ix0;
      const float w01 = (1.f - fy) * fx * wgt * iy0 * ix1;
      const float w10 = fy * (1.f - fx) * wgt * iy1 * ix0;
      const float w11 = fy * fx * wgt * iy1 * ix1;
      const int xc0 = min(max(x0, 0), WW - 1);
      const int xc1 = min(max(x0 + 1, 0), WW - 1);
      const int yc0 = min(max(y0, 0), HH - 1);
      const int yc1 = min(max(y0 + 1, 0), HH - 1);
      const bf16x8 q00 = *(const bf16x8*)(vbase + (size_t)(yc0 * WW + xc0) * HEAD_DIM_);
      const bf16x8 q01 = *(const bf16x8*)(vbase + (size_t)(yc0 * WW + xc1) * HEAD_DIM_);
      const bf16x8 q10 = *(const bf16x8*)(vbase + (size_t)(yc1 * WW + xc0) * HEAD_DIM_);
      const bf16x8 q11 = *(const bf16x8*)(vbase + (size_t)(yc1 * WW + xc1) * HEAD_DIM_);
#pragma unroll
      for (int jj = 0; jj < 8; ++jj) {
        acc[jj] += w00 * bf2f(q00[jj]) + w01 * bf2f(q01[jj]) +
                   w10 * bf2f(q10[jj]) + w11 * bf2f(q11[jj]);
      }
    }
  }
  float* o = tmp + (size_t)row * 256 + h * 32 + c8 * 8;
  f32x4 o0 = {acc[0], acc[1], acc[2], acc[3]};
  f32x4 o1 = {acc[4], acc[5], acc[6], acc[7]};
  *(f32x4*)(o) = o0;
  *(f32x4*)(o + 4) = o1;
}

// ---------------------------------------------------------------------------
extern "C" void kernel_launch(void* const* d_in, const int* in_sizes, int n_in,
                              void* d_out, int out_size, void* d_ws, size_t ws_size,
                              hipStream_t stream) {
  const float* query  = (const float*)d_in[0];
  const float* refpts = (const float*)d_in[1];
  const float* value  = (const float*)d_in[2];
  const float* W_off  = (const float*)d_in[4];
  const float* b_off  = (const float*)d_in[5];
  const float* W_attn = (const float*)d_in[6];
  const float* b_attn = (const float*)d_in[7];
  const float* W_val  = (const float*)d_in[8];
  const float* b_val  = (const float*)d_in[9];
  const float* W_out  = (const float*)d_in[10];
  const float* b_out  = (const float*)d_in[11];
  float* out = (float*)d_out;

  char* ws = (char*)d_ws;
  short* value_p = (short*)ws;                                 // 217,710,592 B
  size_t off = (size_t)BS_ * HEADS_ * LV_ * HEAD_DIM_ * 2;
  float* offsets = (float*)(ws + off); off += (size_t)BS_ * LQ_ * 256 * 4;
  float* attn    = (float*)(ws + off); off += (size_t)BS_ * LQ_ * 128 * 4;
  float* tmp     = (float*)(ws + off); off += (size_t)BS_ * LQ_ * 256 * 4;

  // Aliasing plan (stream-sequential ordering makes each safe):
  //  WtA/WtB in value_p[0:256KB): consumed by query GEMMs BEFORE the
  //    value GEMM overwrites value_p.
  //  logits = tmp: written by attn GEMM, consumed by softmax.
  //  WtV = tmp[0:128KB): written after logits dead; read during the value
  //    GEMM (B-reg prologue + L2); overwritten by sampler output later.
  //  WtO = value_p[0:128KB): written AFTER sampler has read value_p.
  short* WtA = (short*)value_p;
  short* WtB = (short*)value_p + 256 * 256;
  float* logits = tmp;
  short* WtV = (short*)tmp;
  short* WtO = (short*)value_p;

  const int MQ = BS_ * LQ_;   // 9600 = 64*150

  convert_wt<<<256, 256, 0, stream>>>(W_off, WtA, 256);
  convert_wt<<<256, 256, 0, stream>>>(W_attn, WtB, 128);
  gemm_qproj<<<MQ / 64, 256, 0, stream>>>(query, WtA, b_off, offsets, 256, 256);
  gemm_qproj<<<MQ / 64, 256, 0, stream>>>(query, WtB, b_attn, logits, 256, 128);
  softmax16<<<(MQ * HEADS_ + 255) / 256, 256, 0, stream>>>(logits, attn, MQ * HEADS_);
  convert_wt<<<256, 256, 0, stream>>>(W_val, WtV, 256);
  gemm_value_persist<<<PSTRIDE_, 512, 0, stream>>>(value, WtV, b_val, value_p);
  msda_sample<<<(MQ * 32) / 256, 256, 0, stream>>>(refpts, offsets, attn, value_p, tmp);
  convert_wt<<<256, 256, 0, stream>>>(W_out, WtO, 256);
  gemm_qproj<<<MQ / 64, 256, 0, stream>>>(tmp, WtO, b_out, out, 256, 256);
}